// Round 5
// baseline (2079.701 us; speedup 1.0000x reference)
//
#include <hip/hip_runtime.h>
#include <hip/hip_bf16.h>
#include <math.h>

// Problem constants
#define B_ 64
#define T_ 50
#define H_ 256
#define G_ 1024
#define V_ 50000

using f16x8 = __attribute__((ext_vector_type(8))) _Float16;
using f16x2 = __attribute__((ext_vector_type(2))) _Float16;
using f32x4 = __attribute__((ext_vector_type(4))) float;

__device__ __forceinline__ float sigm(float x) { return 1.0f / (1.0f + expf(-x)); }

#if __has_builtin(__builtin_amdgcn_fdot2)
#define FDOT2(a, b, c) __builtin_amdgcn_fdot2((a), (b), (c), false)
#else
__device__ __forceinline__ float fdot2_emul(f16x2 a, f16x2 b, float c)
{ return fmaf((float)a[0], (float)b[0], fmaf((float)a[1], (float)b[1], c)); }
#define FDOT2 fdot2_emul
#endif

// ---------------------------------------------------------------------------
// Embedding gather: x_tm[t*B + b][h] = emb[idx[b*T + t]][h]   (time-major)
// ---------------------------------------------------------------------------
__global__ __launch_bounds__(64) void embed_k(const int* __restrict__ idx,
                                              const float* __restrict__ emb,
                                              float* __restrict__ x_tm)
{
    const int row = blockIdx.x;          // t*B + b
    const int b = row & (B_ - 1);
    const int t = row >> 6;              // /B_
    const int id = idx[b * T_ + t];
    const float4 v = *reinterpret_cast<const float4*>(emb + (size_t)id * H_ + threadIdx.x * 4);
    *reinterpret_cast<float4*>(x_tm + (size_t)row * H_ + threadIdx.x * 4) = v;
}

// ---------------------------------------------------------------------------
// fp32 -> fp16 convert (8 elems/thread), n multiple of 2048
// ---------------------------------------------------------------------------
__global__ __launch_bounds__(256) void conv_half(const float* __restrict__ in,
                                                 _Float16* __restrict__ out, int n)
{
    const int i = (blockIdx.x * 256 + threadIdx.x) * 8;
    if (i + 8 <= n) {
        const float4 v0 = *reinterpret_cast<const float4*>(in + i);
        const float4 v1 = *reinterpret_cast<const float4*>(in + i + 4);
        f16x8 h;
        h[0] = (_Float16)v0.x; h[1] = (_Float16)v0.y;
        h[2] = (_Float16)v0.z; h[3] = (_Float16)v0.w;
        h[4] = (_Float16)v1.x; h[5] = (_Float16)v1.y;
        h[6] = (_Float16)v1.z; h[7] = (_Float16)v1.w;
        *reinterpret_cast<f16x8*>(out + i) = h;
    }
}

// ---------------------------------------------------------------------------
// Pack recurrence weights [256][1024] fp32 -> interleaved half2 quad layout:
//   dst_f16x2[ (k2g*1024 + j)*4 + g ] = ( src[2*k2][j], src[2*k2+1][j] )
//   where k2 = 4*k2g + g.  So a float4 at (k2g, j) holds 4 consecutive
//   k-pairs for column j -> wave reads 1KB contiguous dwordx4.
// grid (128, 3): blockIdx.x = k2, blockIdx.y selects {Uh0, Wx1, Uh1}
// ---------------------------------------------------------------------------
__global__ __launch_bounds__(256) void pack_w_q(const float* __restrict__ Uh0,
                                                const float* __restrict__ Wx1,
                                                const float* __restrict__ Uh1,
                                                f16x2* __restrict__ up0,
                                                f16x2* __restrict__ wx1p,
                                                f16x2* __restrict__ uh1p)
{
    const int k2 = blockIdx.x;           // 0..127
    const int which = blockIdx.y;        // 0..2
    const float* __restrict__ src = (which == 0) ? Uh0 : (which == 1) ? Wx1 : Uh1;
    f16x2* __restrict__ dst = (which == 0) ? up0 : (which == 1) ? wx1p : uh1p;
    const int k2g = k2 >> 2, g = k2 & 3;
#pragma unroll
    for (int i = 0; i < 4; ++i) {
        const int j = threadIdx.x + (i << 8);
        const float lo = src[(size_t)(2 * k2) * G_ + j];
        const float hi = src[(size_t)(2 * k2 + 1) * G_ + j];
        f16x2 p; p[0] = (_Float16)lo; p[1] = (_Float16)hi;
        dst[((size_t)k2g * G_ + j) * 4 + g] = p;
    }
}

// ---------------------------------------------------------------------------
// Tiled fp32 GEMM (xh0 precompute): C[M][N] = A[M][K] * B(K-major)
// ---------------------------------------------------------------------------
__global__ __launch_bounds__(256) void gemm128_kn(const float* __restrict__ A,
                                                  const float* __restrict__ Bm,
                                                  float* __restrict__ C,
                                                  int M, int N, int K)
{
    __shared__ float As[32][132];
    __shared__ float Bs[32][132];

    const int m0 = blockIdx.x * 128;
    const int n0 = blockIdx.y * 128;
    const int tid = threadIdx.x;
    const int tm = (tid >> 4) << 3;
    const int tn = (tid & 15) << 3;

    float acc[8][8];
#pragma unroll
    for (int i = 0; i < 8; ++i)
#pragma unroll
        for (int j = 0; j < 8; ++j) acc[i][j] = 0.0f;

    for (int k0 = 0; k0 < K; k0 += 32) {
#pragma unroll
        for (int i = 0; i < 4; ++i) {
            const int s = tid + (i << 8);
            const int m = s >> 3;
            const int kk = (s & 7) << 2;
            const float4 v = *reinterpret_cast<const float4*>(
                A + (size_t)(m0 + m) * K + k0 + kk);
            As[kk + 0][m] = v.x; As[kk + 1][m] = v.y;
            As[kk + 2][m] = v.z; As[kk + 3][m] = v.w;
        }
#pragma unroll
        for (int i = 0; i < 4; ++i) {
            const int s = tid + (i << 8);
            const int kk = s >> 5;
            const int nn = (s & 31) << 2;
            const float4 v = *reinterpret_cast<const float4*>(
                Bm + (size_t)(k0 + kk) * N + n0 + nn);
            *reinterpret_cast<float4*>(&Bs[kk][nn]) = v;
        }
        __syncthreads();

#pragma unroll
        for (int k = 0; k < 32; ++k) {
            float a[8], bb[8];
            *reinterpret_cast<float4*>(&a[0]) = *reinterpret_cast<const float4*>(&As[k][tm]);
            *reinterpret_cast<float4*>(&a[4]) = *reinterpret_cast<const float4*>(&As[k][tm + 4]);
            *reinterpret_cast<float4*>(&bb[0]) = *reinterpret_cast<const float4*>(&Bs[k][tn]);
            *reinterpret_cast<float4*>(&bb[4]) = *reinterpret_cast<const float4*>(&Bs[k][tn + 4]);
#pragma unroll
            for (int i = 0; i < 8; ++i)
#pragma unroll
                for (int j = 0; j < 8; ++j)
                    acc[i][j] = fmaf(a[i], bb[j], acc[i][j]);
        }
        __syncthreads();
    }

#pragma unroll
    for (int i = 0; i < 8; ++i) {
        const int m = m0 + tm + i;
#pragma unroll
        for (int j = 0; j < 8; j += 4) {
            const int n = n0 + tn + j;
            float4 v;
            v.x = acc[i][j + 0]; v.y = acc[i][j + 1];
            v.z = acc[i][j + 2]; v.w = acc[i][j + 3];
            *reinterpret_cast<float4*>(C + (size_t)m * N + n) = v;
        }
    }
}

// ---------------------------------------------------------------------------
// Persistent MI-LSTM recurrence: one block per batch element, all T steps.
// 1024 threads; thread j owns gate column j. Weights in q-layout: per k-group
// one dwordx4 per thread (wave = 1KB contiguous). h via LDS b128 broadcast.
// ---------------------------------------------------------------------------
__global__ __launch_bounds__(1024) void mi_persist(
    const float4* __restrict__ up0q,    // [32][1024] float4
    const float4* __restrict__ wx1q,    // [32][1024] float4
    const float4* __restrict__ uh1q,    // [32][1024] float4
    const float* __restrict__ xh0,      // [T*B][G]
    _Float16* __restrict__ outsH,       // [B*T][H]
    const float* __restrict__ alpha,    // [2][1024]
    const float* __restrict__ b1,
    const float* __restrict__ b2,
    const float* __restrict__ bsv)
{
    const int b = blockIdx.x;
    const int j = threadIdx.x;

    __shared__ __align__(16) _Float16 h0h[256];
    __shared__ __align__(16) _Float16 h1h[256];
    __shared__ float gs[1024];
    __shared__ float c0s[256], c1s[256];

    if (j < 256) {
        h0h[j] = (_Float16)0.f; h1h[j] = (_Float16)0.f;
        c0s[j] = 0.f; c1s[j] = 0.f;
    }
    const float a0v = alpha[j],      b10v = b1[j],      b20v = b2[j],      bs0v = bsv[j];
    const float a1v = alpha[G_ + j], b11v = b1[G_ + j], b21v = b2[G_ + j], bs1v = bsv[G_ + j];
    __syncthreads();

    const float4* __restrict__ U0 = up0q + j;    // stride 1024 per k-group
    const float4* __restrict__ W1 = wx1q + j;
    const float4* __restrict__ U1 = uh1q + j;

    for (int t = 0; t < T_; ++t) {
        // ---- layer 0: a = (h0 @ Uh0)[j] ----
        float a = 0.f;
#pragma unroll
        for (int kg = 0; kg < 32; ++kg) {
            const float4 w4 = U0[kg << 10];
            const f16x2* wp = reinterpret_cast<const f16x2*>(&w4);
            const f16x8 h8 = *reinterpret_cast<const f16x8*>(&h0h[kg << 3]);
            f16x2 hp;
            hp[0] = h8[0]; hp[1] = h8[1]; a = FDOT2(hp, wp[0], a);
            hp[0] = h8[2]; hp[1] = h8[3]; a = FDOT2(hp, wp[1], a);
            hp[0] = h8[4]; hp[1] = h8[5]; a = FDOT2(hp, wp[2], a);
            hp[0] = h8[6]; hp[1] = h8[7]; a = FDOT2(hp, wp[3], a);
        }
        const float x = xh0[((size_t)(t * B_ + b) << 10) + j];
        gs[j] = a0v * x * a + b10v * x + b20v * a + bs0v;
        __syncthreads();

        if (j < 256) {
            const float gi = gs[j], gj = gs[j + 256], gf = gs[j + 512], go = gs[j + 768];
            const float cn = c0s[j] * sigm(gf + 1.0f) + sigm(gi) * tanhf(gj);
            c0s[j] = cn;
            h0h[j] = (_Float16)(tanhf(cn) * sigm(go));
        }
        __syncthreads();

        // ---- layer 1: xa = (h0new @ Wx1)[j], ha = (h1 @ Uh1)[j] ----
        float xa = 0.f, ha = 0.f;
#pragma unroll
        for (int kg = 0; kg < 32; ++kg) {
            const float4 wx4 = W1[kg << 10];
            const float4 wu4 = U1[kg << 10];
            const f16x2* wxp = reinterpret_cast<const f16x2*>(&wx4);
            const f16x2* wup = reinterpret_cast<const f16x2*>(&wu4);
            const f16x8 h08 = *reinterpret_cast<const f16x8*>(&h0h[kg << 3]);
            const f16x8 h18 = *reinterpret_cast<const f16x8*>(&h1h[kg << 3]);
            f16x2 hp;
            hp[0] = h08[0]; hp[1] = h08[1]; xa = FDOT2(hp, wxp[0], xa);
            hp[0] = h08[2]; hp[1] = h08[3]; xa = FDOT2(hp, wxp[1], xa);
            hp[0] = h08[4]; hp[1] = h08[5]; xa = FDOT2(hp, wxp[2], xa);
            hp[0] = h08[6]; hp[1] = h08[7]; xa = FDOT2(hp, wxp[3], xa);
            hp[0] = h18[0]; hp[1] = h18[1]; ha = FDOT2(hp, wup[0], ha);
            hp[0] = h18[2]; hp[1] = h18[3]; ha = FDOT2(hp, wup[1], ha);
            hp[0] = h18[4]; hp[1] = h18[5]; ha = FDOT2(hp, wup[2], ha);
            hp[0] = h18[6]; hp[1] = h18[7]; ha = FDOT2(hp, wup[3], ha);
        }
        gs[j] = a1v * xa * ha + b11v * xa + b21v * ha + bs1v;
        __syncthreads();

        if (j < 256) {
            const float gi = gs[j], gj = gs[j + 256], gf = gs[j + 512], go = gs[j + 768];
            const float cn = c1s[j] * sigm(gf + 1.0f) + sigm(gi) * tanhf(gj);
            c1s[j] = cn;
            const float hn = tanhf(cn) * sigm(go);
            h1h[j] = (_Float16)hn;
            outsH[((size_t)(b * T_ + t) << 8) + j] = (_Float16)hn;
        }
        __syncthreads();
    }
}

// ---------------------------------------------------------------------------
// Projection: C[3200][50000] = A16[3200][256] * B16[50000][256]^T + bias
// fp16 MFMA 16x16x32, 128x128 tile, 4 waves (2x2), BK=64.
// ---------------------------------------------------------------------------
#define PM 128
#define PN 128
#define PK 64

__device__ __forceinline__ void gload_lds16(const void* g, void* l)
{
    __builtin_amdgcn_global_load_lds(
        (const __attribute__((address_space(1))) unsigned int*)g,
        (__attribute__((address_space(3))) unsigned int*)l, 16, 0, 0);
}

__global__ __launch_bounds__(256) void proj_mfma(
    const _Float16* __restrict__ A16,   // [3200][256]
    const _Float16* __restrict__ B16,   // [50000][256]
    const float* __restrict__ bias,     // [50000]
    float* __restrict__ C)              // [3200][50000]
{
    __shared__ __align__(16) _Float16 Asub[PM * PK];
    __shared__ __align__(16) _Float16 Bsub[PN * PK];

    const int tid = threadIdx.x;
    const int l = tid & 63;
    const int w = tid >> 6;             // wave 0..3
    const int wm = w >> 1, wn = w & 1;  // 2x2 wave grid

    const int n0 = blockIdx.x * PN;     // 0..49920
    const int m0 = blockIdx.y * PM;     // 0..3072

    f32x4 acc[4][4] = {};

    for (int k0 = 0; k0 < H_; k0 += PK) {
#pragma unroll
        for (int is = 0; is < 4; ++is) {
            const int i = is * 256 + tid;          // 0..1023
            const int r = i >> 3;                  // 0..127
            const int ch = (i & 7) ^ (r & 7);      // pre-swizzled source chunk
            gload_lds16(A16 + (size_t)(m0 + r) * H_ + k0 + ch * 8, &Asub[i * 8]);
            int n = n0 + r; if (n > V_ - 1) n = V_ - 1;
            gload_lds16(B16 + (size_t)n * H_ + k0 + ch * 8, &Bsub[i * 8]);
        }
        __syncthreads();

#pragma unroll
        for (int ks = 0; ks < 2; ++ks) {
            f16x8 af[4], bf[4];
#pragma unroll
            for (int i = 0; i < 4; ++i) {
                const int r = wm * 64 + i * 16 + (l & 15);
                const int ch = (ks * 4 + (l >> 4)) ^ (r & 7);
                af[i] = *reinterpret_cast<const f16x8*>(&Asub[r * PK + ch * 8]);
            }
#pragma unroll
            for (int jf = 0; jf < 4; ++jf) {
                const int r = wn * 64 + jf * 16 + (l & 15);
                const int ch = (ks * 4 + (l >> 4)) ^ (r & 7);
                bf[jf] = *reinterpret_cast<const f16x8*>(&Bsub[r * PK + ch * 8]);
            }
#pragma unroll
            for (int i = 0; i < 4; ++i)
#pragma unroll
                for (int jf = 0; jf < 4; ++jf)
                    acc[i][jf] = __builtin_amdgcn_mfma_f32_16x16x32_f16(
                        af[i], bf[jf], acc[i][jf], 0, 0, 0);
        }
        __syncthreads();
    }

    const int rb = (l >> 4) << 2;
    const int cl = l & 15;
#pragma unroll
    for (int jf = 0; jf < 4; ++jf) {
        const int col = n0 + wn * 64 + jf * 16 + cl;
        if (col < V_) {
            const float bv = bias[col];
#pragma unroll
            for (int i = 0; i < 4; ++i) {
                const int rowb = m0 + wm * 64 + i * 16 + rb;
#pragma unroll
                for (int r = 0; r < 4; ++r)
                    C[(size_t)(rowb + r) * V_ + col] = acc[i][jf][r] + bv;
            }
        }
    }
}

// ---------------------------------------------------------------------------
extern "C" void kernel_launch(void* const* d_in, const int* in_sizes, int n_in,
                              void* d_out, int out_size, void* d_ws, size_t ws_size,
                              hipStream_t stream)
{
    const int*   idx   = (const int*)  d_in[0];
    const float* emb   = (const float*)d_in[1];
    const float* Wx    = (const float*)d_in[2];   // [2][256][1024]
    const float* Uh    = (const float*)d_in[3];   // [2][256][1024]
    const float* alpha = (const float*)d_in[4];   // [2][1024]
    const float* b1    = (const float*)d_in[5];
    const float* b2    = (const float*)d_in[6];
    const float* bsv   = (const float*)d_in[7];
    const float* sw    = (const float*)d_in[8];   // [50000][256]
    const float* sb    = (const float*)d_in[9];   // [50000]
    float* out = (float*)d_out;

    // workspace layout (bytes)
    char* wsb = (char*)d_ws;
    float*    x_tm  = (float*)   (wsb);                 //  3,276,800
    float*    xh0   = (float*)   (wsb + 3276800);       // 13,107,200
    _Float16* outsH = (_Float16*)(wsb + 16384000);      //  1,638,400
    _Float16* w16   = (_Float16*)(wsb + 18022400);      // 25,600,000
    f16x2*    up0   = (f16x2*)   (wsb + 43622400);      //    524,288
    f16x2*    wx1p  = (f16x2*)   (wsb + 44146688);      //    524,288
    f16x2*    uh1p  = (f16x2*)   (wsb + 44670976);      //    524,288  (end ~45.2 MB)

    const float* Wx1 = Wx + (size_t)H_ * G_;
    const float* Uh0 = Uh;
    const float* Uh1 = Uh + (size_t)H_ * G_;

    // 0) pack recurrence weights to q-layout half2
    {
        dim3 grid(128, 3);
        pack_w_q<<<grid, 256, 0, stream>>>(Uh0, Wx1, Uh1, up0, wx1p, uh1p);
    }

    // softmax weights -> fp16
    conv_half<<<(V_ * H_) / 2048, 256, 0, stream>>>(sw, w16, V_ * H_);

    // 1) embedding gather (time-major)
    embed_k<<<T_ * B_, 64, 0, stream>>>(idx, emb, x_tm);

    // 2) xh for layer 0, all timesteps: [3200,256] @ [256,1024]
    {
        dim3 grid(3200 / 128, G_ / 128);
        gemm128_kn<<<grid, 256, 0, stream>>>(x_tm, Wx, xh0, 3200, G_, H_);
    }

    // 3) recurrence: single persistent dispatch
    mi_persist<<<B_, 1024, 0, stream>>>((const float4*)up0, (const float4*)wx1p,
                                        (const float4*)uh1p, xh0, outsH,
                                        alpha, b1, b2, bsv);

    // 4) logits = outsH @ w16^T + sb : fp16 MFMA
    {
        dim3 grid((V_ + PN - 1) / PN, 3200 / PM);   // (391, 25)
        proj_mfma<<<grid, 256, 0, stream>>>(outsH, w16, sb, out);
    }
}

// Round 7
// 895.146 us; speedup vs baseline: 2.3233x; 2.3233x over previous
//
#include <hip/hip_runtime.h>
#include <hip/hip_bf16.h>
#include <math.h>

// Problem constants
#define B_ 64
#define T_ 50
#define H_ 256
#define G_ 1024
#define V_ 50000

using f16x8 = __attribute__((ext_vector_type(8))) _Float16;
using f16x2 = __attribute__((ext_vector_type(2))) _Float16;
using f32x4 = __attribute__((ext_vector_type(4))) float;

__device__ __forceinline__ float sigm(float x) { return 1.0f / (1.0f + expf(-x)); }

#if __has_builtin(__builtin_amdgcn_fdot2)
#define FDOT2(a, b, c) __builtin_amdgcn_fdot2((a), (b), (c), false)
#else
__device__ __forceinline__ float fdot2_emul(f16x2 a, f16x2 b, float c)
{ return fmaf((float)a[0], (float)b[0], fmaf((float)a[1], (float)b[1], c)); }
#define FDOT2 fdot2_emul
#endif

// 8-wide fp16 dot with fp32 accumulate; pairs via shufflevector (sub-register,
// no address-taking -> no scratch alloca; that was round-5's 2.4x regression).
__device__ __forceinline__ float dot8(f16x8 h, f16x8 w, float acc)
{
    acc = FDOT2(__builtin_shufflevector(h, h, 0, 1), __builtin_shufflevector(w, w, 0, 1), acc);
    acc = FDOT2(__builtin_shufflevector(h, h, 2, 3), __builtin_shufflevector(w, w, 2, 3), acc);
    acc = FDOT2(__builtin_shufflevector(h, h, 4, 5), __builtin_shufflevector(w, w, 4, 5), acc);
    acc = FDOT2(__builtin_shufflevector(h, h, 6, 7), __builtin_shufflevector(w, w, 6, 7), acc);
    return acc;
}

// ---------------------------------------------------------------------------
// Embedding gather: x_tm[t*B + b][h] = emb[idx[b*T + t]][h]   (time-major)
// ---------------------------------------------------------------------------
__global__ __launch_bounds__(64) void embed_k(const int* __restrict__ idx,
                                              const float* __restrict__ emb,
                                              float* __restrict__ x_tm)
{
    const int row = blockIdx.x;          // t*B + b
    const int b = row & (B_ - 1);
    const int t = row >> 6;              // /B_
    const int id = idx[b * T_ + t];
    const float4 v = *reinterpret_cast<const float4*>(emb + (size_t)id * H_ + threadIdx.x * 4);
    *reinterpret_cast<float4*>(x_tm + (size_t)row * H_ + threadIdx.x * 4) = v;
}

// ---------------------------------------------------------------------------
// fp32 -> fp16 convert (8 elems/thread), n multiple of 2048
// ---------------------------------------------------------------------------
__global__ __launch_bounds__(256) void conv_half(const float* __restrict__ in,
                                                 _Float16* __restrict__ out, int n)
{
    const int i = (blockIdx.x * 256 + threadIdx.x) * 8;
    if (i + 8 <= n) {
        const float4 v0 = *reinterpret_cast<const float4*>(in + i);
        const float4 v1 = *reinterpret_cast<const float4*>(in + i + 4);
        f16x8 h;
        h[0] = (_Float16)v0.x; h[1] = (_Float16)v0.y;
        h[2] = (_Float16)v0.z; h[3] = (_Float16)v0.w;
        h[4] = (_Float16)v1.x; h[5] = (_Float16)v1.y;
        h[6] = (_Float16)v1.z; h[7] = (_Float16)v1.w;
        *reinterpret_cast<f16x8*>(out + i) = h;
    }
}

// ---------------------------------------------------------------------------
// Pack recurrence weights [256][1024] fp32 -> q-layout half2:
//   halves[ ((k2g*1024 + j)*4 + g)*2 + {0,1} ] = src[2*(4*k2g+g) + {0,1}][j]
// Thread j's f16x8 at (k2g, j) holds k = 8*k2g .. 8*k2g+7 for column j.
// grid (128, 3): blockIdx.x = k2, blockIdx.y selects {Uh0, Wx1, Uh1}
// ---------------------------------------------------------------------------
__global__ __launch_bounds__(256) void pack_w_q(const float* __restrict__ Uh0,
                                                const float* __restrict__ Wx1,
                                                const float* __restrict__ Uh1,
                                                f16x2* __restrict__ up0,
                                                f16x2* __restrict__ wx1p,
                                                f16x2* __restrict__ uh1p)
{
    const int k2 = blockIdx.x;           // 0..127
    const int which = blockIdx.y;        // 0..2
    const float* __restrict__ src = (which == 0) ? Uh0 : (which == 1) ? Wx1 : Uh1;
    f16x2* __restrict__ dst = (which == 0) ? up0 : (which == 1) ? wx1p : uh1p;
    const int k2g = k2 >> 2, g = k2 & 3;
#pragma unroll
    for (int i = 0; i < 4; ++i) {
        const int j = threadIdx.x + (i << 8);
        const float lo = src[(size_t)(2 * k2) * G_ + j];
        const float hi = src[(size_t)(2 * k2 + 1) * G_ + j];
        f16x2 p; p[0] = (_Float16)lo; p[1] = (_Float16)hi;
        dst[((size_t)k2g * G_ + j) * 4 + g] = p;
    }
}

// ---------------------------------------------------------------------------
// Tiled fp32 GEMM (xh0 precompute): C[M][N] = A[M][K] * B(K-major)
// ---------------------------------------------------------------------------
__global__ __launch_bounds__(256) void gemm128_kn(const float* __restrict__ A,
                                                  const float* __restrict__ Bm,
                                                  float* __restrict__ C,
                                                  int M, int N, int K)
{
    __shared__ float As[32][132];
    __shared__ float Bs[32][132];

    const int m0 = blockIdx.x * 128;
    const int n0 = blockIdx.y * 128;
    const int tid = threadIdx.x;
    const int tm = (tid >> 4) << 3;
    const int tn = (tid & 15) << 3;

    float acc[8][8];
#pragma unroll
    for (int i = 0; i < 8; ++i)
#pragma unroll
        for (int j = 0; j < 8; ++j) acc[i][j] = 0.0f;

    for (int k0 = 0; k0 < K; k0 += 32) {
#pragma unroll
        for (int i = 0; i < 4; ++i) {
            const int s = tid + (i << 8);
            const int m = s >> 3;
            const int kk = (s & 7) << 2;
            const float4 v = *reinterpret_cast<const float4*>(
                A + (size_t)(m0 + m) * K + k0 + kk);
            As[kk + 0][m] = v.x; As[kk + 1][m] = v.y;
            As[kk + 2][m] = v.z; As[kk + 3][m] = v.w;
        }
#pragma unroll
        for (int i = 0; i < 4; ++i) {
            const int s = tid + (i << 8);
            const int kk = s >> 5;
            const int nn = (s & 31) << 2;
            const float4 v = *reinterpret_cast<const float4*>(
                Bm + (size_t)(k0 + kk) * N + n0 + nn);
            *reinterpret_cast<float4*>(&Bs[kk][nn]) = v;
        }
        __syncthreads();

#pragma unroll
        for (int k = 0; k < 32; ++k) {
            float a[8], bb[8];
            *reinterpret_cast<float4*>(&a[0]) = *reinterpret_cast<const float4*>(&As[k][tm]);
            *reinterpret_cast<float4*>(&a[4]) = *reinterpret_cast<const float4*>(&As[k][tm + 4]);
            *reinterpret_cast<float4*>(&bb[0]) = *reinterpret_cast<const float4*>(&Bs[k][tn]);
            *reinterpret_cast<float4*>(&bb[4]) = *reinterpret_cast<const float4*>(&Bs[k][tn + 4]);
#pragma unroll
            for (int i = 0; i < 8; ++i)
#pragma unroll
                for (int j = 0; j < 8; ++j)
                    acc[i][j] = fmaf(a[i], bb[j], acc[i][j]);
        }
        __syncthreads();
    }

#pragma unroll
    for (int i = 0; i < 8; ++i) {
        const int m = m0 + tm + i;
#pragma unroll
        for (int j = 0; j < 8; j += 4) {
            const int n = n0 + tn + j;
            float4 v;
            v.x = acc[i][j + 0]; v.y = acc[i][j + 1];
            v.z = acc[i][j + 2]; v.w = acc[i][j + 3];
            *reinterpret_cast<float4*>(C + (size_t)m * N + n) = v;
        }
    }
}

// ---------------------------------------------------------------------------
// Persistent MI-LSTM recurrence: one block per batch element, all T steps.
// 1024 threads; thread j owns gate column j. Weights q-layout; per k-group
// one 16B f16x8 load per thread (wave = 1KB contiguous dwordx4).
// ---------------------------------------------------------------------------
__global__ __launch_bounds__(1024) void mi_persist(
    const _Float16* __restrict__ up0q,   // q-layout, 512 KB
    const _Float16* __restrict__ wx1q,
    const _Float16* __restrict__ uh1q,
    const float* __restrict__ xh0,       // [T*B][G]
    _Float16* __restrict__ outsH,        // [B*T][H]
    const float* __restrict__ alpha,     // [2][1024]
    const float* __restrict__ b1,
    const float* __restrict__ b2,
    const float* __restrict__ bsv)
{
    const int b = blockIdx.x;
    const int j = threadIdx.x;

    __shared__ __align__(16) _Float16 h0h[256];
    __shared__ __align__(16) _Float16 h1h[256];
    __shared__ float gs[1024];
    __shared__ float c0s[256], c1s[256];

    if (j < 256) {
        h0h[j] = (_Float16)0.f; h1h[j] = (_Float16)0.f;
        c0s[j] = 0.f; c1s[j] = 0.f;
    }
    const float a0v = alpha[j],      b10v = b1[j],      b20v = b2[j],      bs0v = bsv[j];
    const float a1v = alpha[G_ + j], b11v = b1[G_ + j], b21v = b2[G_ + j], bs1v = bsv[G_ + j];
    __syncthreads();

    // element (half) offsets: thread j's f16x8 for k-group kg lives at
    // (kg*1024 + j)*8  ->  base j*8, stride kg<<13
    const _Float16* __restrict__ U0 = up0q + (size_t)j * 8;
    const _Float16* __restrict__ W1 = wx1q + (size_t)j * 8;
    const _Float16* __restrict__ U1 = uh1q + (size_t)j * 8;

    for (int t = 0; t < T_; ++t) {
        // ---- layer 0: a = (h0 @ Uh0)[j] ----
        float a = 0.f;
#pragma unroll 8
        for (int kg = 0; kg < 32; ++kg) {
            const f16x8 w8 = *reinterpret_cast<const f16x8*>(U0 + ((size_t)kg << 13));
            const f16x8 h8 = *reinterpret_cast<const f16x8*>(&h0h[kg << 3]);
            a = dot8(h8, w8, a);
        }
        const float x = xh0[((size_t)(t * B_ + b) << 10) + j];
        gs[j] = a0v * x * a + b10v * x + b20v * a + bs0v;
        __syncthreads();

        if (j < 256) {
            const float gi = gs[j], gj = gs[j + 256], gf = gs[j + 512], go = gs[j + 768];
            const float cn = c0s[j] * sigm(gf + 1.0f) + sigm(gi) * tanhf(gj);
            c0s[j] = cn;
            h0h[j] = (_Float16)(tanhf(cn) * sigm(go));
        }
        __syncthreads();

        // ---- layer 1: xa = (h0new @ Wx1)[j], ha = (h1 @ Uh1)[j] ----
        float xa = 0.f, ha = 0.f;
#pragma unroll 4
        for (int kg = 0; kg < 32; ++kg) {
            const f16x8 wx8 = *reinterpret_cast<const f16x8*>(W1 + ((size_t)kg << 13));
            const f16x8 wu8 = *reinterpret_cast<const f16x8*>(U1 + ((size_t)kg << 13));
            const f16x8 h08 = *reinterpret_cast<const f16x8*>(&h0h[kg << 3]);
            const f16x8 h18 = *reinterpret_cast<const f16x8*>(&h1h[kg << 3]);
            xa = dot8(h08, wx8, xa);
            ha = dot8(h18, wu8, ha);
        }
        gs[j] = a1v * xa * ha + b11v * xa + b21v * ha + bs1v;
        __syncthreads();

        if (j < 256) {
            const float gi = gs[j], gj = gs[j + 256], gf = gs[j + 512], go = gs[j + 768];
            const float cn = c1s[j] * sigm(gf + 1.0f) + sigm(gi) * tanhf(gj);
            c1s[j] = cn;
            const float hn = tanhf(cn) * sigm(go);
            h1h[j] = (_Float16)hn;
            outsH[((size_t)(b * T_ + t) << 8) + j] = (_Float16)hn;
        }
        __syncthreads();
    }
}

// ---------------------------------------------------------------------------
// Projection: C[3200][50000] = A16[3200][256] * B16[50000][256]^T + bias
// fp16 MFMA 16x16x32, 128x128 tile, 4 waves (2x2), BK=64.
// ---------------------------------------------------------------------------
#define PM 128
#define PN 128
#define PK 64

__device__ __forceinline__ void gload_lds16(const void* g, void* l)
{
    __builtin_amdgcn_global_load_lds(
        (const __attribute__((address_space(1))) unsigned int*)g,
        (__attribute__((address_space(3))) unsigned int*)l, 16, 0, 0);
}

__global__ __launch_bounds__(256) void proj_mfma(
    const _Float16* __restrict__ A16,   // [3200][256]
    const _Float16* __restrict__ B16,   // [50000][256]
    const float* __restrict__ bias,     // [50000]
    float* __restrict__ C)              // [3200][50000]
{
    __shared__ __align__(16) _Float16 Asub[PM * PK];
    __shared__ __align__(16) _Float16 Bsub[PN * PK];

    const int tid = threadIdx.x;
    const int l = tid & 63;
    const int w = tid >> 6;             // wave 0..3
    const int wm = w >> 1, wn = w & 1;  // 2x2 wave grid

    const int n0 = blockIdx.x * PN;     // 0..49920
    const int m0 = blockIdx.y * PM;     // 0..3072

    f32x4 acc[4][4] = {};

    for (int k0 = 0; k0 < H_; k0 += PK) {
#pragma unroll
        for (int is = 0; is < 4; ++is) {
            const int i = is * 256 + tid;          // 0..1023
            const int r = i >> 3;                  // 0..127
            const int ch = (i & 7) ^ (r & 7);      // pre-swizzled source chunk
            gload_lds16(A16 + (size_t)(m0 + r) * H_ + k0 + ch * 8, &Asub[i * 8]);
            int n = n0 + r; if (n > V_ - 1) n = V_ - 1;
            gload_lds16(B16 + (size_t)n * H_ + k0 + ch * 8, &Bsub[i * 8]);
        }
        __syncthreads();

#pragma unroll
        for (int ks = 0; ks < 2; ++ks) {
            f16x8 af[4], bf[4];
#pragma unroll
            for (int i = 0; i < 4; ++i) {
                const int r = wm * 64 + i * 16 + (l & 15);
                const int ch = (ks * 4 + (l >> 4)) ^ (r & 7);
                af[i] = *reinterpret_cast<const f16x8*>(&Asub[r * PK + ch * 8]);
            }
#pragma unroll
            for (int jf = 0; jf < 4; ++jf) {
                const int r = wn * 64 + jf * 16 + (l & 15);
                const int ch = (ks * 4 + (l >> 4)) ^ (r & 7);
                bf[jf] = *reinterpret_cast<const f16x8*>(&Bsub[r * PK + ch * 8]);
            }
#pragma unroll
            for (int i = 0; i < 4; ++i)
#pragma unroll
                for (int jf = 0; jf < 4; ++jf)
                    acc[i][jf] = __builtin_amdgcn_mfma_f32_16x16x32_f16(
                        af[i], bf[jf], acc[i][jf], 0, 0, 0);
        }
        __syncthreads();
    }

    const int rb = (l >> 4) << 2;
    const int cl = l & 15;
#pragma unroll
    for (int jf = 0; jf < 4; ++jf) {
        const int col = n0 + wn * 64 + jf * 16 + cl;
        if (col < V_) {
            const float bv = bias[col];
#pragma unroll
            for (int i = 0; i < 4; ++i) {
                const int rowb = m0 + wm * 64 + i * 16 + rb;
#pragma unroll
                for (int r = 0; r < 4; ++r)
                    C[(size_t)(rowb + r) * V_ + col] = acc[i][jf][r] + bv;
            }
        }
    }
}

// ---------------------------------------------------------------------------
extern "C" void kernel_launch(void* const* d_in, const int* in_sizes, int n_in,
                              void* d_out, int out_size, void* d_ws, size_t ws_size,
                              hipStream_t stream)
{
    const int*   idx   = (const int*)  d_in[0];
    const float* emb   = (const float*)d_in[1];
    const float* Wx    = (const float*)d_in[2];   // [2][256][1024]
    const float* Uh    = (const float*)d_in[3];   // [2][256][1024]
    const float* alpha = (const float*)d_in[4];   // [2][1024]
    const float* b1    = (const float*)d_in[5];
    const float* b2    = (const float*)d_in[6];
    const float* bsv   = (const float*)d_in[7];
    const float* sw    = (const float*)d_in[8];   // [50000][256]
    const float* sb    = (const float*)d_in[9];   // [50000]
    float* out = (float*)d_out;

    // workspace layout (bytes)
    char* wsb = (char*)d_ws;
    float*    x_tm  = (float*)   (wsb);                 //  3,276,800
    float*    xh0   = (float*)   (wsb + 3276800);       // 13,107,200
    _Float16* outsH = (_Float16*)(wsb + 16384000);      //  1,638,400
    _Float16* w16   = (_Float16*)(wsb + 18022400);      // 25,600,000
    f16x2*    up0   = (f16x2*)   (wsb + 43622400);      //    524,288
    f16x2*    wx1p  = (f16x2*)   (wsb + 44146688);      //    524,288
    f16x2*    uh1p  = (f16x2*)   (wsb + 44670976);      //    524,288  (end ~45.2 MB)

    const float* Wx1 = Wx + (size_t)H_ * G_;
    const float* Uh0 = Uh;
    const float* Uh1 = Uh + (size_t)H_ * G_;

    // 0) pack recurrence weights to q-layout half2
    {
        dim3 grid(128, 3);
        pack_w_q<<<grid, 256, 0, stream>>>(Uh0, Wx1, Uh1, up0, wx1p, uh1p);
    }

    // softmax weights -> fp16
    conv_half<<<(V_ * H_) / 2048, 256, 0, stream>>>(sw, w16, V_ * H_);

    // 1) embedding gather (time-major)
    embed_k<<<T_ * B_, 64, 0, stream>>>(idx, emb, x_tm);

    // 2) xh for layer 0, all timesteps: [3200,256] @ [256,1024]
    {
        dim3 grid(3200 / 128, G_ / 128);
        gemm128_kn<<<grid, 256, 0, stream>>>(x_tm, Wx, xh0, 3200, G_, H_);
    }

    // 3) recurrence: single persistent dispatch
    mi_persist<<<B_, 1024, 0, stream>>>((const _Float16*)up0, (const _Float16*)wx1p,
                                        (const _Float16*)uh1p, xh0, outsH,
                                        alpha, b1, b2, bsv);

    // 4) logits = outsH @ w16^T + sb : fp16 MFMA
    {
        dim3 grid((V_ + PN - 1) / PN, 3200 / PM);   // (391, 25)
        proj_mfma<<<grid, 256, 0, stream>>>(outsH, w16, sb, out);
    }
}

// Round 8
// 813.799 us; speedup vs baseline: 2.5555x; 1.1000x over previous
//
#include <hip/hip_runtime.h>
#include <hip/hip_bf16.h>
#include <math.h>

// Problem constants
#define B_ 64
#define T_ 50
#define H_ 256
#define G_ 1024
#define V_ 50000
#define NBLK 32

using f16x8 = __attribute__((ext_vector_type(8))) _Float16;
using f32x4 = __attribute__((ext_vector_type(4))) float;

__device__ __forceinline__ float sigm(float x) { return 1.0f / (1.0f + expf(-x)); }

// ---------------------------------------------------------------------------
// Embedding gather: x_tm[t*B + b][h] = emb[idx[b*T + t]][h]   (time-major)
// ---------------------------------------------------------------------------
__global__ __launch_bounds__(64) void embed_k(const int* __restrict__ idx,
                                              const float* __restrict__ emb,
                                              float* __restrict__ x_tm)
{
    const int row = blockIdx.x;          // t*B + b
    const int b = row & (B_ - 1);
    const int t = row >> 6;              // /B_
    const int id = idx[b * T_ + t];
    const float4 v = *reinterpret_cast<const float4*>(emb + (size_t)id * H_ + threadIdx.x * 4);
    *reinterpret_cast<float4*>(x_tm + (size_t)row * H_ + threadIdx.x * 4) = v;
}

// ---------------------------------------------------------------------------
// fp32 -> fp16 convert (8 elems/thread), n multiple of 2048
// ---------------------------------------------------------------------------
__global__ __launch_bounds__(256) void conv_half(const float* __restrict__ in,
                                                 _Float16* __restrict__ out, int n)
{
    const int i = (blockIdx.x * 256 + threadIdx.x) * 8;
    if (i + 8 <= n) {
        const float4 v0 = *reinterpret_cast<const float4*>(in + i);
        const float4 v1 = *reinterpret_cast<const float4*>(in + i + 4);
        f16x8 h;
        h[0] = (_Float16)v0.x; h[1] = (_Float16)v0.y;
        h[2] = (_Float16)v0.z; h[3] = (_Float16)v0.w;
        h[4] = (_Float16)v1.x; h[5] = (_Float16)v1.y;
        h[6] = (_Float16)v1.z; h[7] = (_Float16)v1.w;
        *reinterpret_cast<f16x8*>(out + i) = h;
    }
}

// ---------------------------------------------------------------------------
// Pack recurrence weights for column-partitioned blocks:
//   wpk[c][m][col32][k] fp16, c = block (owns h-dims 8c..8c+7),
//   m in {Uh0, Wx1, Uh1}, col32 = g*8+u -> global col g*256 + 8c + u.
// grid (32, 3), 256 threads.
// ---------------------------------------------------------------------------
__global__ __launch_bounds__(256) void pack_w_rec(const float* __restrict__ Uh0,
                                                  const float* __restrict__ Wx1,
                                                  const float* __restrict__ Uh1,
                                                  _Float16* __restrict__ wpk)
{
    const int c = blockIdx.x;            // 0..31
    const int m = blockIdx.y;            // 0..2
    const float* __restrict__ src = (m == 0) ? Uh0 : (m == 1) ? Wx1 : Uh1;
    _Float16* __restrict__ dst = wpk + (((size_t)c * 3 + m) << 13);
    for (int i = threadIdx.x; i < 8192; i += 256) {
        const int k = i >> 5;            // 0..255
        const int col = i & 31;          // g*8 + u
        const int colg = ((col >> 3) << 8) + (c << 3) + (col & 7);
        dst[(col << 8) + k] = (_Float16)src[(size_t)k * G_ + colg];
    }
}

// ---------------------------------------------------------------------------
// Tiled fp32 GEMM (xh0 precompute): C[M][N] = A[M][K] * B(K-major)
// ---------------------------------------------------------------------------
__global__ __launch_bounds__(256) void gemm128_kn(const float* __restrict__ A,
                                                  const float* __restrict__ Bm,
                                                  float* __restrict__ C,
                                                  int M, int N, int K)
{
    __shared__ float As[32][132];
    __shared__ float Bs[32][132];

    const int m0 = blockIdx.x * 128;
    const int n0 = blockIdx.y * 128;
    const int tid = threadIdx.x;
    const int tm = (tid >> 4) << 3;
    const int tn = (tid & 15) << 3;

    float acc[8][8];
#pragma unroll
    for (int i = 0; i < 8; ++i)
#pragma unroll
        for (int j = 0; j < 8; ++j) acc[i][j] = 0.0f;

    for (int k0 = 0; k0 < K; k0 += 32) {
#pragma unroll
        for (int i = 0; i < 4; ++i) {
            const int s = tid + (i << 8);
            const int m = s >> 3;
            const int kk = (s & 7) << 2;
            const float4 v = *reinterpret_cast<const float4*>(
                A + (size_t)(m0 + m) * K + k0 + kk);
            As[kk + 0][m] = v.x; As[kk + 1][m] = v.y;
            As[kk + 2][m] = v.z; As[kk + 3][m] = v.w;
        }
#pragma unroll
        for (int i = 0; i < 4; ++i) {
            const int s = tid + (i << 8);
            const int kk = s >> 5;
            const int nn = (s & 31) << 2;
            const float4 v = *reinterpret_cast<const float4*>(
                Bm + (size_t)(k0 + kk) * N + n0 + nn);
            *reinterpret_cast<float4*>(&Bs[kk][nn]) = v;
        }
        __syncthreads();

#pragma unroll
        for (int k = 0; k < 32; ++k) {
            float a[8], bb[8];
            *reinterpret_cast<float4*>(&a[0]) = *reinterpret_cast<const float4*>(&As[k][tm]);
            *reinterpret_cast<float4*>(&a[4]) = *reinterpret_cast<const float4*>(&As[k][tm + 4]);
            *reinterpret_cast<float4*>(&bb[0]) = *reinterpret_cast<const float4*>(&Bs[k][tn]);
            *reinterpret_cast<float4*>(&bb[4]) = *reinterpret_cast<const float4*>(&Bs[k][tn + 4]);
#pragma unroll
            for (int i = 0; i < 8; ++i)
#pragma unroll
                for (int j = 0; j < 8; ++j)
                    acc[i][j] = fmaf(a[i], bb[j], acc[i][j]);
        }
        __syncthreads();
    }

#pragma unroll
    for (int i = 0; i < 8; ++i) {
        const int m = m0 + tm + i;
#pragma unroll
        for (int j = 0; j < 8; j += 4) {
            const int n = n0 + tn + j;
            float4 v;
            v.x = acc[i][j + 0]; v.y = acc[i][j + 1];
            v.z = acc[i][j + 2]; v.w = acc[i][j + 3];
            *reinterpret_cast<float4*>(C + (size_t)m * N + n) = v;
        }
    }
}

// ---------------------------------------------------------------------------
// Grid barrier (device-scope), one slot per barrier event, pre-zeroed.
// ---------------------------------------------------------------------------
__device__ __forceinline__ void gbar_arrive(int* slot)
{
    __syncthreads();                     // all block stores done
    if (threadIdx.x == 0) {
        __threadfence();                 // flush to device-coherent point
        __hip_atomic_fetch_add(slot, 1, __ATOMIC_RELAXED, __HIP_MEMORY_SCOPE_AGENT);
    }
}

__device__ __forceinline__ void gbar_wait(int* slot)
{
    if (threadIdx.x == 0) {
        while (__hip_atomic_load(slot, __ATOMIC_RELAXED, __HIP_MEMORY_SCOPE_AGENT) < NBLK)
            __builtin_amdgcn_s_sleep(2);
    }
    __syncthreads();
    __threadfence();                     // acquire: invalidate stale caches
}

// ---------------------------------------------------------------------------
// Column-partitioned persistent MI-LSTM recurrence.
// 32 blocks x 256 threads; block c owns h-dims [8c, 8c+8) (32 gate cols/layer).
// Weights LDS-resident (48 KB). Per step: 3 MFMA matmuls [64,256]@[256,32],
// h exchanged via global fp16 buffers (double-buffered by t parity) + grid
// barriers (2/step). Uh1 matmul scheduled inside the barrier-wait window.
// ---------------------------------------------------------------------------
__global__ __launch_bounds__(256) void mi_rec(
    const _Float16* __restrict__ wpk,   // [32][3][32][256]
    const float* __restrict__ xh0,      // [T*B][G] fp32
    _Float16* __restrict__ h0x,         // [2][64][256]
    _Float16* __restrict__ h1x,         // [2][64][256]
    _Float16* __restrict__ outsH,       // [B*T][H]
    int* __restrict__ bars,             // [2*T], zeroed
    const float* __restrict__ alpha, const float* __restrict__ b1,
    const float* __restrict__ b2, const float* __restrict__ bsv)
{
    __shared__ __align__(16) _Float16 h0l[16384];   // [64][256] swizzled
    __shared__ __align__(16) _Float16 h1l[16384];
    __shared__ __align__(16) _Float16 wl[24576];    // [3][32][256] swizzled
    __shared__ float gA[2112], gB[2112];            // [64][33]
    __shared__ float c0l[512], c1l[512];            // [64][8]

    const int c = blockIdx.x;
    const int tid = threadIdx.x;
    const int l = tid & 63;
    const int w = tid >> 6;

    // zero state
    for (int i = tid; i < 2048; i += 256) {
        *reinterpret_cast<f16x8*>(&h0l[i << 3]) = f16x8{};
        *reinterpret_cast<f16x8*>(&h1l[i << 3]) = f16x8{};
    }
    for (int i = tid; i < 512; i += 256) { c0l[i] = 0.f; c1l[i] = 0.f; }

    // stage packed weights -> LDS with chunk swizzle
    for (int i = tid; i < 3072; i += 256) {
        const int m = i >> 10;
        const int col = (i >> 5) & 31;
        const int ch = i & 31;
        const f16x8 v = *reinterpret_cast<const f16x8*>(
            &wpk[(((size_t)c * 3 + m) * 32 + col) * 256 + (ch << 3)]);
        *reinterpret_cast<f16x8*>(
            &wl[(m * 32 + col) * 256 + ((ch ^ (col & 7)) << 3)]) = v;
    }

    const int u = tid & 7, b0 = tid >> 3;           // b0: 0..31
    const int jl = (c << 3) + u;
    float al0[4], b10[4], b20[4], bs0[4], al1[4], b11[4], b21[4], bs1[4];
#pragma unroll
    for (int g = 0; g < 4; ++g) {
        const int col = (g << 8) + jl;
        al0[g] = alpha[col];        b10[g] = b1[col];
        b20[g] = b2[col];           bs0[g] = bsv[col];
        al1[g] = alpha[G_ + col];   b11[g] = b1[G_ + col];
        b21[g] = b2[G_ + col];      bs1[g] = bsv[G_ + col];
    }
    __syncthreads();

    const int arow = (w << 4) + (l & 15);           // batch row for A frags
    const int cA = l & 15, cB = 16 + (l & 15);      // owned-col indices
    const int kq = l >> 4;

    auto MM = [&](const _Float16* __restrict__ am, const _Float16* __restrict__ bm,
                  f32x4& A0, f32x4& A1) {
#pragma unroll
        for (int s = 0; s < 8; ++s) {
            const int ck = (s << 2) + kq;
            const f16x8 af = *reinterpret_cast<const f16x8*>(
                &am[(arow << 8) + ((ck ^ (arow & 7)) << 3)]);
            const f16x8 bf0 = *reinterpret_cast<const f16x8*>(
                &bm[(cA << 8) + ((ck ^ (cA & 7)) << 3)]);
            const f16x8 bf1 = *reinterpret_cast<const f16x8*>(
                &bm[(cB << 8) + ((ck ^ (cB & 7)) << 3)]);
            A0 = __builtin_amdgcn_mfma_f32_16x16x32_f16(af, bf0, A0, 0, 0, 0);
            A1 = __builtin_amdgcn_mfma_f32_16x16x32_f16(af, bf1, A1, 0, 0, 0);
        }
    };

    auto STG = [&](float* gl, f32x4 A0, f32x4 A1) {
        const int rb = (w << 4) + (kq << 2);
#pragma unroll
        for (int r = 0; r < 4; ++r) {
            gl[(rb + r) * 33 + cA] = A0[r];
            gl[(rb + r) * 33 + cB] = A1[r];
        }
    };

    auto STAGE_H = [&](const _Float16* __restrict__ src, _Float16* __restrict__ dst) {
#pragma unroll
        for (int it = 0; it < 8; ++it) {
            const int idx = (it << 8) + tid;
            const int row = idx >> 5, ch = idx & 31;
            const f16x8 v = *reinterpret_cast<const f16x8*>(&src[(row << 8) + (ch << 3)]);
            *reinterpret_cast<f16x8*>(&dst[(row << 8) + ((ch ^ (row & 7)) << 3)]) = v;
        }
    };

    for (int t = 0; t < T_; ++t) {
        const int p = t & 1;
        _Float16* __restrict__ h0w = h0x + (p << 14);
        _Float16* __restrict__ h1w = h1x + (p << 14);
        const _Float16* __restrict__ h1r = h1x + ((p ^ 1) << 14);

        // ---- phase A: layer-0 matmul + gates + h0 write ----
        f32x4 A0 = {}, A1 = {};
        MM(h0l, wl, A0, A1);                 // Uh0
        STG(gA, A0, A1);
        __syncthreads();
#pragma unroll
        for (int bb = 0; bb < 2; ++bb) {
            const int b = b0 + (bb << 5);
            float g4[4];
#pragma unroll
            for (int g = 0; g < 4; ++g) {
                const float a = gA[b * 33 + (g << 3) + u];
                const float x = xh0[(((size_t)(t * B_ + b)) << 10) + (g << 8) + jl];
                g4[g] = al0[g] * x * a + b10[g] * x + b20[g] * a + bs0[g];
            }
            const float cn = c0l[(b << 3) + u] * sigm(g4[2] + 1.f)
                           + sigm(g4[0]) * tanhf(g4[1]);
            c0l[(b << 3) + u] = cn;
            h0w[(b << 8) + jl] = (_Float16)(tanhf(cn) * sigm(g4[3]));
        }
        gbar_arrive(&bars[2 * t]);

        // ---- phase B: Uh1 * h1(prev) while h0 exchange is in flight ----
        if (t > 0) {
            gbar_wait(&bars[2 * t - 1]);
            STAGE_H(h1r, h1l);
            __syncthreads();
        }
        f32x4 H0 = {}, H1 = {};
        MM(h1l, wl + 2 * 8192, H0, H1);      // Uh1

        // ---- phase C: Wx1 * h0(new) + gates + h1 write ----
        gbar_wait(&bars[2 * t]);
        STAGE_H(h0w, h0l);
        __syncthreads();
        f32x4 X0 = {}, X1 = {};
        MM(h0l, wl + 1 * 8192, X0, X1);      // Wx1
        STG(gA, X0, X1);
        STG(gB, H0, H1);
        __syncthreads();
#pragma unroll
        for (int bb = 0; bb < 2; ++bb) {
            const int b = b0 + (bb << 5);
            float g4[4];
#pragma unroll
            for (int g = 0; g < 4; ++g) {
                const float xa = gA[b * 33 + (g << 3) + u];
                const float ha = gB[b * 33 + (g << 3) + u];
                g4[g] = al1[g] * xa * ha + b11[g] * xa + b21[g] * ha + bs1[g];
            }
            const float cn = c1l[(b << 3) + u] * sigm(g4[2] + 1.f)
                           + sigm(g4[0]) * tanhf(g4[1]);
            c1l[(b << 3) + u] = cn;
            const float hn = tanhf(cn) * sigm(g4[3]);
            h1w[(b << 8) + jl] = (_Float16)hn;
            outsH[(((size_t)b * T_ + t) << 8) + jl] = (_Float16)hn;
        }
        gbar_arrive(&bars[2 * t + 1]);
    }
}

// ---------------------------------------------------------------------------
// Projection: C[3200][50000] = A16[3200][256] * B16[50000][256]^T + bias
// fp16 MFMA 16x16x32, 128x128 tile, 4 waves (2x2), BK=64.
// ---------------------------------------------------------------------------
#define PM 128
#define PN 128
#define PK 64

__device__ __forceinline__ void gload_lds16(const void* g, void* l)
{
    __builtin_amdgcn_global_load_lds(
        (const __attribute__((address_space(1))) unsigned int*)g,
        (__attribute__((address_space(3))) unsigned int*)l, 16, 0, 0);
}

__global__ __launch_bounds__(256) void proj_mfma(
    const _Float16* __restrict__ A16,   // [3200][256]
    const _Float16* __restrict__ B16,   // [50000][256]
    const float* __restrict__ bias,     // [50000]
    float* __restrict__ C)              // [3200][50000]
{
    __shared__ __align__(16) _Float16 Asub[PM * PK];
    __shared__ __align__(16) _Float16 Bsub[PN * PK];

    const int tid = threadIdx.x;
    const int l = tid & 63;
    const int w = tid >> 6;             // wave 0..3
    const int wm = w >> 1, wn = w & 1;  // 2x2 wave grid

    const int n0 = blockIdx.x * PN;     // 0..49920
    const int m0 = blockIdx.y * PM;     // 0..3072

    f32x4 acc[4][4] = {};

    for (int k0 = 0; k0 < H_; k0 += PK) {
#pragma unroll
        for (int is = 0; is < 4; ++is) {
            const int i = is * 256 + tid;          // 0..1023
            const int r = i >> 3;                  // 0..127
            const int ch = (i & 7) ^ (r & 7);      // pre-swizzled source chunk
            gload_lds16(A16 + (size_t)(m0 + r) * H_ + k0 + ch * 8, &Asub[i * 8]);
            int n = n0 + r; if (n > V_ - 1) n = V_ - 1;
            gload_lds16(B16 + (size_t)n * H_ + k0 + ch * 8, &Bsub[i * 8]);
        }
        __syncthreads();

#pragma unroll
        for (int ks = 0; ks < 2; ++ks) {
            f16x8 af[4], bf[4];
#pragma unroll
            for (int i = 0; i < 4; ++i) {
                const int r = wm * 64 + i * 16 + (l & 15);
                const int ch = (ks * 4 + (l >> 4)) ^ (r & 7);
                af[i] = *reinterpret_cast<const f16x8*>(&Asub[r * PK + ch * 8]);
            }
#pragma unroll
            for (int jf = 0; jf < 4; ++jf) {
                const int r = wn * 64 + jf * 16 + (l & 15);
                const int ch = (ks * 4 + (l >> 4)) ^ (r & 7);
                bf[jf] = *reinterpret_cast<const f16x8*>(&Bsub[r * PK + ch * 8]);
            }
#pragma unroll
            for (int i = 0; i < 4; ++i)
#pragma unroll
                for (int jf = 0; jf < 4; ++jf)
                    acc[i][jf] = __builtin_amdgcn_mfma_f32_16x16x32_f16(
                        af[i], bf[jf], acc[i][jf], 0, 0, 0);
        }
        __syncthreads();
    }

    const int rb = (l >> 4) << 2;
    const int cl = l & 15;
#pragma unroll
    for (int jf = 0; jf < 4; ++jf) {
        const int col = n0 + wn * 64 + jf * 16 + cl;
        if (col < V_) {
            const float bv = bias[col];
#pragma unroll
            for (int i = 0; i < 4; ++i) {
                const int rowb = m0 + wm * 64 + i * 16 + rb;
#pragma unroll
                for (int r = 0; r < 4; ++r)
                    C[(size_t)(rowb + r) * V_ + col] = acc[i][jf][r] + bv;
            }
        }
    }
}

// ---------------------------------------------------------------------------
extern "C" void kernel_launch(void* const* d_in, const int* in_sizes, int n_in,
                              void* d_out, int out_size, void* d_ws, size_t ws_size,
                              hipStream_t stream)
{
    const int*   idx   = (const int*)  d_in[0];
    const float* emb   = (const float*)d_in[1];
    const float* Wx    = (const float*)d_in[2];   // [2][256][1024]
    const float* Uh    = (const float*)d_in[3];   // [2][256][1024]
    const float* alpha = (const float*)d_in[4];   // [2][1024]
    const float* b1    = (const float*)d_in[5];
    const float* b2    = (const float*)d_in[6];
    const float* bsv   = (const float*)d_in[7];
    const float* sw    = (const float*)d_in[8];   // [50000][256]
    const float* sb    = (const float*)d_in[9];   // [50000]
    float* out = (float*)d_out;

    // workspace layout (bytes)
    char* wsb = (char*)d_ws;
    float*    x_tm  = (float*)   (wsb);                 //  3,276,800
    float*    xh0   = (float*)   (wsb + 3276800);       // 13,107,200
    _Float16* outsH = (_Float16*)(wsb + 16384000);      //  1,638,400
    _Float16* w16   = (_Float16*)(wsb + 18022400);      // 25,600,000
    _Float16* wpk   = (_Float16*)(wsb + 43622400);      //  1,572,864
    _Float16* h0x   = (_Float16*)(wsb + 45195264);      //     65,536
    _Float16* h1x   = (_Float16*)(wsb + 45260800);      //     65,536
    int*      bars  = (int*)     (wsb + 45326336);      //        512

    const float* Wx1 = Wx + (size_t)H_ * G_;
    const float* Uh0 = Uh;
    const float* Uh1 = Uh + (size_t)H_ * G_;

    // zero barrier slots (must precede mi_rec every call)
    hipMemsetAsync(bars, 0, 512, stream);

    // 0) pack recurrence weights (column-partitioned, fp16)
    {
        dim3 grid(NBLK, 3);
        pack_w_rec<<<grid, 256, 0, stream>>>(Uh0, Wx1, Uh1, wpk);
    }

    // softmax weights -> fp16
    conv_half<<<(V_ * H_) / 2048, 256, 0, stream>>>(sw, w16, V_ * H_);

    // 1) embedding gather (time-major)
    embed_k<<<T_ * B_, 64, 0, stream>>>(idx, emb, x_tm);

    // 2) xh for layer 0, all timesteps: [3200,256] @ [256,1024]
    {
        dim3 grid(3200 / 128, G_ / 128);
        gemm128_kn<<<grid, 256, 0, stream>>>(x_tm, Wx, xh0, 3200, G_, H_);
    }

    // 3) recurrence: 32-block cooperative persistent kernel
    mi_rec<<<NBLK, 256, 0, stream>>>(wpk, xh0, h0x, h1x, outsH, bars,
                                     alpha, b1, b2, bsv);

    // 4) logits = outsH @ w16^T + sb : fp16 MFMA
    {
        dim3 grid((V_ + PN - 1) / PN, 3200 / PM);   // (391, 25)
        proj_mfma<<<grid, 256, 0, stream>>>(outsH, w16, sb, out);
    }
}

// Round 9
// 724.140 us; speedup vs baseline: 2.8720x; 1.1238x over previous
//
#include <hip/hip_runtime.h>
#include <hip/hip_bf16.h>
#include <math.h>

// Problem constants
#define B_ 64
#define T_ 50
#define H_ 256
#define G_ 1024
#define V_ 50000
#define NBLK 32

using f16x8 = __attribute__((ext_vector_type(8))) _Float16;
using f32x4 = __attribute__((ext_vector_type(4))) float;

__device__ __forceinline__ float sigm(float x) { return 1.0f / (1.0f + expf(-x)); }

// ---------------------------------------------------------------------------
// Embedding gather: x_tm[t*B + b][h] = emb[idx[b*T + t]][h]   (time-major)
// ---------------------------------------------------------------------------
__global__ __launch_bounds__(64) void embed_k(const int* __restrict__ idx,
                                              const float* __restrict__ emb,
                                              float* __restrict__ x_tm)
{
    const int row = blockIdx.x;          // t*B + b
    const int b = row & (B_ - 1);
    const int t = row >> 6;              // /B_
    const int id = idx[b * T_ + t];
    const float4 v = *reinterpret_cast<const float4*>(emb + (size_t)id * H_ + threadIdx.x * 4);
    *reinterpret_cast<float4*>(x_tm + (size_t)row * H_ + threadIdx.x * 4) = v;
}

// ---------------------------------------------------------------------------
// fp32 -> fp16 convert (8 elems/thread), n multiple of 2048
// ---------------------------------------------------------------------------
__global__ __launch_bounds__(256) void conv_half(const float* __restrict__ in,
                                                 _Float16* __restrict__ out, int n)
{
    const int i = (blockIdx.x * 256 + threadIdx.x) * 8;
    if (i + 8 <= n) {
        const float4 v0 = *reinterpret_cast<const float4*>(in + i);
        const float4 v1 = *reinterpret_cast<const float4*>(in + i + 4);
        f16x8 h;
        h[0] = (_Float16)v0.x; h[1] = (_Float16)v0.y;
        h[2] = (_Float16)v0.z; h[3] = (_Float16)v0.w;
        h[4] = (_Float16)v1.x; h[5] = (_Float16)v1.y;
        h[6] = (_Float16)v1.z; h[7] = (_Float16)v1.w;
        *reinterpret_cast<f16x8*>(out + i) = h;
    }
}

// ---------------------------------------------------------------------------
// Pack recurrence weights for column-partitioned blocks:
//   wpk[c][m][col32][k] fp16, c = block (owns h-dims 8c..8c+7),
//   m in {Uh0, Wx1, Uh1}, col32 = g*8+u -> global col g*256 + 8c + u.
// grid (32, 3), 256 threads.
// ---------------------------------------------------------------------------
__global__ __launch_bounds__(256) void pack_w_rec(const float* __restrict__ Uh0,
                                                  const float* __restrict__ Wx1,
                                                  const float* __restrict__ Uh1,
                                                  _Float16* __restrict__ wpk)
{
    const int c = blockIdx.x;            // 0..31
    const int m = blockIdx.y;            // 0..2
    const float* __restrict__ src = (m == 0) ? Uh0 : (m == 1) ? Wx1 : Uh1;
    _Float16* __restrict__ dst = wpk + (((size_t)c * 3 + m) << 13);
    for (int i = threadIdx.x; i < 8192; i += 256) {
        const int k = i >> 5;            // 0..255
        const int col = i & 31;          // g*8 + u
        const int colg = ((col >> 3) << 8) + (c << 3) + (col & 7);
        dst[(col << 8) + k] = (_Float16)src[(size_t)k * G_ + colg];
    }
}

// ---------------------------------------------------------------------------
// Tiled fp32 GEMM (xh0 precompute): C[M][N] = A[M][K] * B(K-major)
// ---------------------------------------------------------------------------
__global__ __launch_bounds__(256) void gemm128_kn(const float* __restrict__ A,
                                                  const float* __restrict__ Bm,
                                                  float* __restrict__ C,
                                                  int M, int N, int K)
{
    __shared__ float As[32][132];
    __shared__ float Bs[32][132];

    const int m0 = blockIdx.x * 128;
    const int n0 = blockIdx.y * 128;
    const int tid = threadIdx.x;
    const int tm = (tid >> 4) << 3;
    const int tn = (tid & 15) << 3;

    float acc[8][8];
#pragma unroll
    for (int i = 0; i < 8; ++i)
#pragma unroll
        for (int j = 0; j < 8; ++j) acc[i][j] = 0.0f;

    for (int k0 = 0; k0 < K; k0 += 32) {
#pragma unroll
        for (int i = 0; i < 4; ++i) {
            const int s = tid + (i << 8);
            const int m = s >> 3;
            const int kk = (s & 7) << 2;
            const float4 v = *reinterpret_cast<const float4*>(
                A + (size_t)(m0 + m) * K + k0 + kk);
            As[kk + 0][m] = v.x; As[kk + 1][m] = v.y;
            As[kk + 2][m] = v.z; As[kk + 3][m] = v.w;
        }
#pragma unroll
        for (int i = 0; i < 4; ++i) {
            const int s = tid + (i << 8);
            const int kk = s >> 5;
            const int nn = (s & 31) << 2;
            const float4 v = *reinterpret_cast<const float4*>(
                Bm + (size_t)(k0 + kk) * N + n0 + nn);
            *reinterpret_cast<float4*>(&Bs[kk][nn]) = v;
        }
        __syncthreads();

#pragma unroll
        for (int k = 0; k < 32; ++k) {
            float a[8], bb[8];
            *reinterpret_cast<float4*>(&a[0]) = *reinterpret_cast<const float4*>(&As[k][tm]);
            *reinterpret_cast<float4*>(&a[4]) = *reinterpret_cast<const float4*>(&As[k][tm + 4]);
            *reinterpret_cast<float4*>(&bb[0]) = *reinterpret_cast<const float4*>(&Bs[k][tn]);
            *reinterpret_cast<float4*>(&bb[4]) = *reinterpret_cast<const float4*>(&Bs[k][tn + 4]);
#pragma unroll
            for (int i = 0; i < 8; ++i)
#pragma unroll
                for (int j = 0; j < 8; ++j)
                    acc[i][j] = fmaf(a[i], bb[j], acc[i][j]);
        }
        __syncthreads();
    }

#pragma unroll
    for (int i = 0; i < 8; ++i) {
        const int m = m0 + tm + i;
#pragma unroll
        for (int j = 0; j < 8; j += 4) {
            const int n = n0 + tn + j;
            float4 v;
            v.x = acc[i][j + 0]; v.y = acc[i][j + 1];
            v.z = acc[i][j + 2]; v.w = acc[i][j + 3];
            *reinterpret_cast<float4*>(C + (size_t)m * N + n) = v;
        }
    }
}

// ---------------------------------------------------------------------------
// Grid barrier (device-scope), one slot per barrier event, pre-zeroed.
// ---------------------------------------------------------------------------
__device__ __forceinline__ void gbar_arrive(int* slot)
{
    __syncthreads();                     // all block stores done
    if (threadIdx.x == 0) {
        __threadfence();                 // flush to device-coherent point
        __hip_atomic_fetch_add(slot, 1, __ATOMIC_RELAXED, __HIP_MEMORY_SCOPE_AGENT);
    }
}

__device__ __forceinline__ void gbar_wait(int* slot)
{
    if (threadIdx.x == 0) {
        while (__hip_atomic_load(slot, __ATOMIC_RELAXED, __HIP_MEMORY_SCOPE_AGENT) < NBLK)
            __builtin_amdgcn_s_sleep(1);
    }
    __syncthreads();
    __threadfence();                     // acquire: invalidate stale caches
}

// ---------------------------------------------------------------------------
// Column-partitioned persistent MI-LSTM recurrence, layer-1 pipelined one
// step behind layer-0: superstep s computes h0(s) and h1(s-1), then ONE
// exchange+barrier (50 barriers total instead of 100).
// 32 blocks x 256 threads; block c owns h-dims [8c, 8c+8) (32 gate cols/layer).
// Weights LDS-resident (48 KB).
// ---------------------------------------------------------------------------
__global__ __launch_bounds__(256) void mi_rec(
    const _Float16* __restrict__ wpk,   // [32][3][32][256]
    const float* __restrict__ xh0,      // [T*B][G] fp32
    _Float16* __restrict__ h0x,         // [2][64][256]
    _Float16* __restrict__ h1x,         // [2][64][256]
    _Float16* __restrict__ outsH,       // [B*T][H]
    int* __restrict__ bars,             // [T], zeroed
    const float* __restrict__ alpha, const float* __restrict__ b1,
    const float* __restrict__ b2, const float* __restrict__ bsv)
{
    __shared__ __align__(16) _Float16 h0l[16384];   // [64][256] swizzled
    __shared__ __align__(16) _Float16 h1l[16384];
    __shared__ __align__(16) _Float16 wl[24576];    // [3][32][256] swizzled
    __shared__ float gA[2112], gB[2112];            // [64][33]
    __shared__ float c0l[512], c1l[512];            // [64][8]

    const int c = blockIdx.x;
    const int tid = threadIdx.x;
    const int l = tid & 63;
    const int w = tid >> 6;

    // zero state
    for (int i = tid; i < 2048; i += 256) {
        *reinterpret_cast<f16x8*>(&h0l[i << 3]) = f16x8{};
        *reinterpret_cast<f16x8*>(&h1l[i << 3]) = f16x8{};
    }
    for (int i = tid; i < 512; i += 256) { c0l[i] = 0.f; c1l[i] = 0.f; }

    // stage packed weights -> LDS with chunk swizzle
    for (int i = tid; i < 3072; i += 256) {
        const int m = i >> 10;
        const int col = (i >> 5) & 31;
        const int ch = i & 31;
        const f16x8 v = *reinterpret_cast<const f16x8*>(
            &wpk[(((size_t)c * 3 + m) * 32 + col) * 256 + (ch << 3)]);
        *reinterpret_cast<f16x8*>(
            &wl[(m * 32 + col) * 256 + ((ch ^ (col & 7)) << 3)]) = v;
    }

    const int u = tid & 7, b0 = tid >> 3;           // b0: 0..31
    const int jl = (c << 3) + u;
    float al0[4], b10[4], b20[4], bs0[4], al1[4], b11[4], b21[4], bs1[4];
#pragma unroll
    for (int g = 0; g < 4; ++g) {
        const int col = (g << 8) + jl;
        al0[g] = alpha[col];        b10[g] = b1[col];
        b20[g] = b2[col];           bs0[g] = bsv[col];
        al1[g] = alpha[G_ + col];   b11[g] = b1[G_ + col];
        b21[g] = b2[G_ + col];      bs1[g] = bsv[G_ + col];
    }
    __syncthreads();

    const int arow = (w << 4) + (l & 15);           // batch row for A frags
    const int cA = l & 15, cB = 16 + (l & 15);      // owned-col indices
    const int kq = l >> 4;

    auto MM = [&](const _Float16* __restrict__ am, const _Float16* __restrict__ bm,
                  f32x4& A0, f32x4& A1) {
#pragma unroll
        for (int s = 0; s < 8; ++s) {
            const int ck = (s << 2) + kq;
            const f16x8 af = *reinterpret_cast<const f16x8*>(
                &am[(arow << 8) + ((ck ^ (arow & 7)) << 3)]);
            const f16x8 bf0 = *reinterpret_cast<const f16x8*>(
                &bm[(cA << 8) + ((ck ^ (cA & 7)) << 3)]);
            const f16x8 bf1 = *reinterpret_cast<const f16x8*>(
                &bm[(cB << 8) + ((ck ^ (cB & 7)) << 3)]);
            A0 = __builtin_amdgcn_mfma_f32_16x16x32_f16(af, bf0, A0, 0, 0, 0);
            A1 = __builtin_amdgcn_mfma_f32_16x16x32_f16(af, bf1, A1, 0, 0, 0);
        }
    };

    auto STG = [&](float* gl, f32x4 A0, f32x4 A1) {
        const int rb = (w << 4) + (kq << 2);
#pragma unroll
        for (int r = 0; r < 4; ++r) {
            gl[(rb + r) * 33 + cA] = A0[r];
            gl[(rb + r) * 33 + cB] = A1[r];
        }
    };

    auto STAGE_H = [&](const _Float16* __restrict__ src, _Float16* __restrict__ dst) {
#pragma unroll
        for (int it = 0; it < 8; ++it) {
            const int idx = (it << 8) + tid;
            const int row = idx >> 5, ch = idx & 31;
            const f16x8 v = *reinterpret_cast<const f16x8*>(&src[(row << 8) + (ch << 3)]);
            *reinterpret_cast<f16x8*>(&dst[(row << 8) + ((ch ^ (row & 7)) << 3)]) = v;
        }
    };

    // supersteps: s computes h0(s) [layer0] and h1(s-1) [layer1]
    for (int s = 0; s <= T_; ++s) {
        const int p = s & 1;
        _Float16* __restrict__ h0w = h0x + (p << 14);
        _Float16* __restrict__ h1w = h1x + (p << 14);

        // ---- layer 0: h0(s) from h0l = h0(s-1) ----
        if (s < T_) {
            f32x4 A0 = {}, A1 = {};
            MM(h0l, wl, A0, A1);                 // Uh0
            STG(gA, A0, A1);
            __syncthreads();
#pragma unroll
            for (int bb = 0; bb < 2; ++bb) {
                const int b = b0 + (bb << 5);
                float g4[4];
#pragma unroll
                for (int g = 0; g < 4; ++g) {
                    const float a = gA[b * 33 + (g << 3) + u];
                    const float x = xh0[(((size_t)(s * B_ + b)) << 10) + (g << 8) + jl];
                    g4[g] = al0[g] * x * a + b10[g] * x + b20[g] * a + bs0[g];
                }
                const float cn = c0l[(b << 3) + u] * sigm(g4[2] + 1.f)
                               + sigm(g4[0]) * tanhf(g4[1]);
                c0l[(b << 3) + u] = cn;
                h0w[(b << 8) + jl] = (_Float16)(tanhf(cn) * sigm(g4[3]));
            }
            __syncthreads();                     // gA free for reuse below
        }

        // ---- layer 1: h1(s-1) from h0l = h0(s-1), h1l = h1(s-2) ----
        if (s > 0) {
            f32x4 X0 = {}, X1 = {}, H0 = {}, H1 = {};
            MM(h0l, wl + 1 * 8192, X0, X1);      // Wx1 * h0(s-1)
            MM(h1l, wl + 2 * 8192, H0, H1);      // Uh1 * h1(s-2)
            STG(gA, X0, X1);
            STG(gB, H0, H1);
            __syncthreads();
#pragma unroll
            for (int bb = 0; bb < 2; ++bb) {
                const int b = b0 + (bb << 5);
                float g4[4];
#pragma unroll
                for (int g = 0; g < 4; ++g) {
                    const float xa = gA[b * 33 + (g << 3) + u];
                    const float ha = gB[b * 33 + (g << 3) + u];
                    g4[g] = al1[g] * xa * ha + b11[g] * xa + b21[g] * ha + bs1[g];
                }
                const float cn = c1l[(b << 3) + u] * sigm(g4[2] + 1.f)
                               + sigm(g4[0]) * tanhf(g4[1]);
                c1l[(b << 3) + u] = cn;
                const float hn = tanhf(cn) * sigm(g4[3]);
                h1w[(b << 8) + jl] = (_Float16)hn;
                outsH[(((size_t)b * T_ + (s - 1)) << 8) + jl] = (_Float16)hn;
            }
        }

        // ---- single exchange + barrier (skip after final superstep) ----
        if (s < T_) {
            gbar_arrive(&bars[s]);
            gbar_wait(&bars[s]);
            STAGE_H(h0w, h0l);                   // h0(s) -> LDS
            if (s > 0) STAGE_H(h1w, h1l);        // h1(s-1) -> LDS
            __syncthreads();
        }
    }
}

// ---------------------------------------------------------------------------
// Projection: C[3200][50000] = A16[3200][256] * B16[50000][256]^T + bias
// fp16 MFMA 16x16x32, 128x128 tile, 4 waves (2x2), BK=64.
// ---------------------------------------------------------------------------
#define PM 128
#define PN 128
#define PK 64

__device__ __forceinline__ void gload_lds16(const void* g, void* l)
{
    __builtin_amdgcn_global_load_lds(
        (const __attribute__((address_space(1))) unsigned int*)g,
        (__attribute__((address_space(3))) unsigned int*)l, 16, 0, 0);
}

__global__ __launch_bounds__(256) void proj_mfma(
    const _Float16* __restrict__ A16,   // [3200][256]
    const _Float16* __restrict__ B16,   // [50000][256]
    const float* __restrict__ bias,     // [50000]
    float* __restrict__ C)              // [3200][50000]
{
    __shared__ __align__(16) _Float16 Asub[PM * PK];
    __shared__ __align__(16) _Float16 Bsub[PN * PK];

    const int tid = threadIdx.x;
    const int l = tid & 63;
    const int w = tid >> 6;             // wave 0..3
    const int wm = w >> 1, wn = w & 1;  // 2x2 wave grid

    const int n0 = blockIdx.x * PN;     // 0..49920
    const int m0 = blockIdx.y * PM;     // 0..3072

    f32x4 acc[4][4] = {};

    for (int k0 = 0; k0 < H_; k0 += PK) {
#pragma unroll
        for (int is = 0; is < 4; ++is) {
            const int i = is * 256 + tid;          // 0..1023
            const int r = i >> 3;                  // 0..127
            const int ch = (i & 7) ^ (r & 7);      // pre-swizzled source chunk
            gload_lds16(A16 + (size_t)(m0 + r) * H_ + k0 + ch * 8, &Asub[i * 8]);
            int n = n0 + r; if (n > V_ - 1) n = V_ - 1;
            gload_lds16(B16 + (size_t)n * H_ + k0 + ch * 8, &Bsub[i * 8]);
        }
        __syncthreads();

#pragma unroll
        for (int ks = 0; ks < 2; ++ks) {
            f16x8 af[4], bf[4];
#pragma unroll
            for (int i = 0; i < 4; ++i) {
                const int r = wm * 64 + i * 16 + (l & 15);
                const int ch = (ks * 4 + (l >> 4)) ^ (r & 7);
                af[i] = *reinterpret_cast<const f16x8*>(&Asub[r * PK + ch * 8]);
            }
#pragma unroll
            for (int jf = 0; jf < 4; ++jf) {
                const int r = wn * 64 + jf * 16 + (l & 15);
                const int ch = (ks * 4 + (l >> 4)) ^ (r & 7);
                bf[jf] = *reinterpret_cast<const f16x8*>(&Bsub[r * PK + ch * 8]);
            }
#pragma unroll
            for (int i = 0; i < 4; ++i)
#pragma unroll
                for (int jf = 0; jf < 4; ++jf)
                    acc[i][jf] = __builtin_amdgcn_mfma_f32_16x16x32_f16(
                        af[i], bf[jf], acc[i][jf], 0, 0, 0);
        }
        __syncthreads();
    }

    const int rb = (l >> 4) << 2;
    const int cl = l & 15;
#pragma unroll
    for (int jf = 0; jf < 4; ++jf) {
        const int col = n0 + wn * 64 + jf * 16 + cl;
        if (col < V_) {
            const float bv = bias[col];
#pragma unroll
            for (int i = 0; i < 4; ++i) {
                const int rowb = m0 + wm * 64 + i * 16 + rb;
#pragma unroll
                for (int r = 0; r < 4; ++r)
                    C[(size_t)(rowb + r) * V_ + col] = acc[i][jf][r] + bv;
            }
        }
    }
}

// ---------------------------------------------------------------------------
extern "C" void kernel_launch(void* const* d_in, const int* in_sizes, int n_in,
                              void* d_out, int out_size, void* d_ws, size_t ws_size,
                              hipStream_t stream)
{
    const int*   idx   = (const int*)  d_in[0];
    const float* emb   = (const float*)d_in[1];
    const float* Wx    = (const float*)d_in[2];   // [2][256][1024]
    const float* Uh    = (const float*)d_in[3];   // [2][256][1024]
    const float* alpha = (const float*)d_in[4];   // [2][1024]
    const float* b1    = (const float*)d_in[5];
    const float* b2    = (const float*)d_in[6];
    const float* bsv   = (const float*)d_in[7];
    const float* sw    = (const float*)d_in[8];   // [50000][256]
    const float* sb    = (const float*)d_in[9];   // [50000]
    float* out = (float*)d_out;

    // workspace layout (bytes)
    char* wsb = (char*)d_ws;
    float*    x_tm  = (float*)   (wsb);                 //  3,276,800
    float*    xh0   = (float*)   (wsb + 3276800);       // 13,107,200
    _Float16* outsH = (_Float16*)(wsb + 16384000);      //  1,638,400
    _Float16* w16   = (_Float16*)(wsb + 18022400);      // 25,600,000
    _Float16* wpk   = (_Float16*)(wsb + 43622400);      //  1,572,864
    _Float16* h0x   = (_Float16*)(wsb + 45195264);      //     65,536
    _Float16* h1x   = (_Float16*)(wsb + 45260800);      //     65,536
    int*      bars  = (int*)     (wsb + 45326336);      //        512

    const float* Wx1 = Wx + (size_t)H_ * G_;
    const float* Uh0 = Uh;
    const float* Uh1 = Uh + (size_t)H_ * G_;

    // zero barrier slots (must precede mi_rec every call)
    hipMemsetAsync(bars, 0, 512, stream);

    // 0) pack recurrence weights (column-partitioned, fp16)
    {
        dim3 grid(NBLK, 3);
        pack_w_rec<<<grid, 256, 0, stream>>>(Uh0, Wx1, Uh1, wpk);
    }

    // softmax weights -> fp16
    conv_half<<<(V_ * H_) / 2048, 256, 0, stream>>>(sw, w16, V_ * H_);

    // 1) embedding gather (time-major)
    embed_k<<<T_ * B_, 64, 0, stream>>>(idx, emb, x_tm);

    // 2) xh for layer 0, all timesteps: [3200,256] @ [256,1024]
    {
        dim3 grid(3200 / 128, G_ / 128);
        gemm128_kn<<<grid, 256, 0, stream>>>(x_tm, Wx, xh0, 3200, G_, H_);
    }

    // 3) recurrence: 32-block cooperative persistent kernel (pipelined)
    mi_rec<<<NBLK, 256, 0, stream>>>(wpk, xh0, h0x, h1x, outsH, bars,
                                     alpha, b1, b2, bsv);

    // 4) logits = outsH @ w16^T + sb : fp16 MFMA
    {
        dim3 grid((V_ + PN - 1) / PN, 3200 / PM);   // (391, 25)
        proj_mfma<<<grid, 256, 0, stream>>>(outsH, w16, sb, out);
    }
}